// Round 6
// baseline (167.061 us; speedup 1.0000x reference)
//
#include <hip/hip_runtime.h>
#include <hip/hip_bf16.h>

#define D 128
#define RPW 8        // rows per wave in spmm
#define NSLICE 8     // channel slices (one per XCD)
#define SCH 16       // channels per slice

typedef __attribute__((ext_vector_type(8))) short bf16x8;
typedef __attribute__((ext_vector_type(4))) float f32x4;

// float -> bf16 bits, round-to-nearest-even
__device__ __forceinline__ unsigned short f2bf(float f) {
    union { float f; unsigned u; } uf{f};
    unsigned r = uf.u + 0x7fffu + ((uf.u >> 16) & 1u);
    return (unsigned short)(r >> 16);
}
__device__ __forceinline__ unsigned pack2(float a, float b) {
    return (unsigned)f2bf(a) | ((unsigned)f2bf(b) << 16);
}
__device__ __forceinline__ float bflo(unsigned u) {
    union { unsigned u; float f; } c{u << 16};
    return c.f;
}
__device__ __forceinline__ float bfhi(unsigned u) {
    union { unsigned u; float f; } c{u & 0xffff0000u};
    return c.f;
}

// ---------------------------------------------------------------------------
// Kernel 0: rowptr[r] = (start,end) from sorted adj_rows; empty rows filled
//           from the gaps (no memset needed). Also converts W to bf16.
// ---------------------------------------------------------------------------
__global__ __launch_bounds__(256) void build_rowptr(const int* __restrict__ rows,
                                                    const float* __restrict__ W,
                                                    unsigned short* __restrict__ wbf,
                                                    int2* __restrict__ rowptr,
                                                    int e, int n) {
    int i = blockIdx.x * 256 + threadIdx.x;
    if (i < D * D) wbf[i] = f2bf(W[i]);
    if (i >= e) return;
    int r = rows[i];
    int prev = (i == 0) ? -1 : rows[i - 1];
    int next = (i == e - 1) ? n : rows[i + 1];
    if (prev != r) {
        rowptr[r].x = i;
        for (int q = prev + 1; q < r; ++q) rowptr[q] = make_int2(i, i);   // empty rows
    }
    if (next != r) {
        rowptr[r].y = i + 1;
        if (i == e - 1)
            for (int q = r + 1; q < n; ++q) rowptr[q] = make_int2(e, e); // trailing empties
    }
}

// ---------------------------------------------------------------------------
// Kernel 1: wi = bf16(x @ W^T), MFMA with swapped operands (D = W·x^T).
//   Coalesced fp32 x loads -> xor-swizzled bf16 LDS -> fragments.
//   Output written in XCD-sliced layout: wi[slice][node][16ch].
// ---------------------------------------------------------------------------
__global__ __launch_bounds__(256) void gemm_mfma(const float* __restrict__ x,
                                                 const unsigned short* __restrict__ wbf,
                                                 unsigned short* __restrict__ wi,
                                                 int nrows) {
    __shared__ __align__(16) unsigned short Xs[128 * 128];

    const int tid = threadIdx.x;
    const int row0 = blockIdx.x * 128;

#pragma unroll
    for (int it = 0; it < 16; ++it) {
        int f = it * 1024 + tid * 4;
        int r = f >> 7, k = f & 127;
        int idx = (r * 128 + k) ^ ((r & 7) << 3);
        int gr = min(row0 + r, nrows - 1);
        float4 xv = *(const float4*)(x + (size_t)gr * D + k);
        *(uint2*)&Xs[idx] = make_uint2(pack2(xv.x, xv.y), pack2(xv.z, xv.w));
    }
    __syncthreads();

    const int lane = tid & 63;
    const int m_base = (tid >> 6) * 32;   // wave's 32 nodes within tile
    const int lrow = lane & 15;
    const int lk8 = (lane >> 4) * 8;

    // B operand: x fragments from LDS
    bf16x8 xfrag[2][4];
#pragma unroll
    for (int xb = 0; xb < 2; ++xb)
#pragma unroll
        for (int kb = 0; kb < 4; ++kb) {
            int r = m_base + xb * 16 + lrow;
            int k = kb * 32 + lk8;
            int idx = (r * 128 + k) ^ ((r & 7) << 3);
            xfrag[xb][kb] = *(const bf16x8*)&Xs[idx];
        }

    f32x4 acc[2][8];
#pragma unroll
    for (int xb = 0; xb < 2; ++xb)
#pragma unroll
        for (int cb = 0; cb < 8; ++cb)
            acc[xb][cb] = (f32x4){0.f, 0.f, 0.f, 0.f};

#pragma unroll
    for (int cb = 0; cb < 8; ++cb) {
#pragma unroll
        for (int kb = 0; kb < 4; ++kb) {
            // A operand: W row (channel) from L1-resident global
            bf16x8 wfrag = *(const bf16x8*)(wbf + (cb * 16 + lrow) * 128 + kb * 32 + lk8);
            acc[0][cb] = __builtin_amdgcn_mfma_f32_16x16x32_bf16(wfrag, xfrag[0][kb], acc[0][cb], 0, 0, 0);
            acc[1][cb] = __builtin_amdgcn_mfma_f32_16x16x32_bf16(wfrag, xfrag[1][kb], acc[1][cb], 0, 0, 0);
        }
    }

    // D layout: col(lane&15)=node, row((lane>>4)*4+j)=channel. cb == slice.
#pragma unroll
    for (int xb = 0; xb < 2; ++xb) {
        int g = row0 + m_base + xb * 16 + lrow;
        if (g < nrows) {
#pragma unroll
            for (int cb = 0; cb < 8; ++cb) {
                uint2 o;
                o.x = pack2(acc[xb][cb][0], acc[xb][cb][1]);
                o.y = pack2(acc[xb][cb][2], acc[xb][cb][3]);
                *(uint2*)(wi + ((size_t)cb * nrows + g) * SCH + (lane >> 4) * 4) = o;
            }
        }
    }
}

// ---------------------------------------------------------------------------
// Kernel 2: out[r] = relu(bias + sum vals[e]*wi[cols[e]])
//   XCD channel-sliced: block's slice = blockIdx&7 (round-robins to XCDs),
//   so each XCD gathers only from its private 3.2MB slice -> L2-resident.
//   Per wave: 8 rows, prefetch-next-row pipeline; 8-edge subgroups, each lane
//   gathers one dword (2 channels); xor-reduce over lanes {8,16,32}.
// ---------------------------------------------------------------------------
__global__ __launch_bounds__(256) void spmm_relu(const unsigned short* __restrict__ wi,
                                                 const int2* __restrict__ rowptr,
                                                 const int* __restrict__ cols,
                                                 const float* __restrict__ vals,
                                                 const float* __restrict__ bias,
                                                 float* __restrict__ out,
                                                 int n) {
    const int lane = threadIdx.x & 63;
    const int s = blockIdx.x & (NSLICE - 1);
    const int rg = blockIdx.x >> 3;
    const int R0 = (rg * 4 + (threadIdx.x >> 6)) * RPW;
    if (R0 >= n) return;
    const int nr = min(RPW, n - R0);

    const unsigned short* ws = wi + (size_t)s * n * SCH;
    const int2 rp = rowptr[R0 + min(lane, nr - 1)];
    const int chp = lane & 7;    // channel-pair index within slice
    const int sub = lane >> 3;   // edge subgroup 0..7

    const float2 bv = *(const float2*)(bias + s * SCH + chp * 2);

    // prologue: stage row 0's first chunk (coalesced)
    int st = __shfl(rp.x, 0), en = __shfl(rp.y, 0);
    int c = 0; float v = 0.f;
    { int idx = st + lane; if (idx < en) { c = cols[idx]; v = vals[idx]; } }

    for (int j = 0; j < nr; ++j) {
        // prefetch next row's metadata (hides latency under this row)
        int st_n = 0, en_n = 0, c_n = 0; float v_n = 0.f;
        if (j + 1 < nr) {
            st_n = __shfl(rp.x, j + 1); en_n = __shfl(rp.y, j + 1);
            int idx = st_n + lane; if (idx < en_n) { c_n = cols[idx]; v_n = vals[idx]; }
        }

        float ax = 0.f, ay = 0.f;
        const int cnt = min(en - st, 64);
        for (int q = 0; q < cnt; q += 16) {          // 16 edges, 2 gathers in flight
            int   c0 = __shfl(c, q + sub);
            int   c1 = __shfl(c, q + 8 + sub);
            float v0 = __shfl(v, q + sub);
            float v1 = __shfl(v, q + 8 + sub);
            unsigned u0 = *(const unsigned*)(ws + (size_t)c0 * SCH + chp * 2);
            unsigned u1 = *(const unsigned*)(ws + (size_t)c1 * SCH + chp * 2);
            ax = fmaf(v0, bflo(u0), ax); ay = fmaf(v0, bfhi(u0), ay);
            ax = fmaf(v1, bflo(u1), ax); ay = fmaf(v1, bfhi(u1), ay);
        }
        // rare rows with >64 edges
        for (int base = st + 64; base < en; base += 64) {
            int cc = 0; float vv = 0.f;
            { int idx = base + lane; if (idx < en) { cc = cols[idx]; vv = vals[idx]; } }
            const int cnt2 = min(en - base, 64);
            for (int q = 0; q < cnt2; q += 16) {
                int   c0 = __shfl(cc, q + sub);
                int   c1 = __shfl(cc, q + 8 + sub);
                float v0 = __shfl(vv, q + sub);
                float v1 = __shfl(vv, q + 8 + sub);
                unsigned u0 = *(const unsigned*)(ws + (size_t)c0 * SCH + chp * 2);
                unsigned u1 = *(const unsigned*)(ws + (size_t)c1 * SCH + chp * 2);
                ax = fmaf(v0, bflo(u0), ax); ay = fmaf(v0, bfhi(u0), ay);
                ax = fmaf(v1, bflo(u1), ax); ay = fmaf(v1, bfhi(u1), ay);
            }
        }

        // reduce across the 8 edge-subgroups (lane bits 3,4,5)
        ax += __shfl_xor(ax, 8); ax += __shfl_xor(ax, 16); ax += __shfl_xor(ax, 32);
        ay += __shfl_xor(ay, 8); ay += __shfl_xor(ay, 16); ay += __shfl_xor(ay, 32);

        if (lane < 8) {
            float2 o;
            o.x = fmaxf(ax + bv.x, 0.f);
            o.y = fmaxf(ay + bv.y, 0.f);
            *(float2*)(out + (size_t)(R0 + j) * D + s * SCH + chp * 2) = o;
        }

        st = st_n; en = en_n; c = c_n; v = v_n;
    }
}

// ---------------------------------------------------------------------------
extern "C" void kernel_launch(void* const* d_in, const int* in_sizes, int n_in,
                              void* d_out, int out_size, void* d_ws, size_t ws_size,
                              hipStream_t stream) {
    const float* x        = (const float*)d_in[0];
    const int*   adj_rows = (const int*)d_in[1];
    const int*   adj_cols = (const int*)d_in[2];
    const float* adj_vals = (const float*)d_in[3];
    const float* weight   = (const float*)d_in[4];
    const float* bias     = (const float*)d_in[5];
    float*       out      = (float*)d_out;

    const int n = in_sizes[0] / D;   // 100000
    const int e = in_sizes[1];       // 1600000

    // workspace layout
    unsigned short* wi = (unsigned short*)d_ws;                 // [8][n][16] bf16 = 25.6 MB
    size_t off = ((size_t)n * D * sizeof(unsigned short) + 255) & ~(size_t)255;
    int2* rowptr = (int2*)((char*)d_ws + off);                  // n int2 = 0.8 MB
    unsigned short* wbf = (unsigned short*)(rowptr + n);        // 32 KB bf16 W

    build_rowptr<<<(e + 255) / 256, 256, 0, stream>>>(adj_rows, weight, wbf,
                                                      rowptr, e, n);

    gemm_mfma<<<(n + 127) / 128, 256, 0, stream>>>(x, wbf, wi, n);

    const int rowgroups = (n + 4 * RPW - 1) / (4 * RPW);
    spmm_relu<<<rowgroups * NSLICE, 256, 0, stream>>>(wi, rowptr, adj_cols, adj_vals,
                                                      bias, out, n);
}

// Round 7
// 96.144 us; speedup vs baseline: 1.7376x; 1.7376x over previous
//
#include <hip/hip_runtime.h>
#include <hip/hip_bf16.h>

#define D 128
#define RPW 8   // rows per wave in spmm

typedef __attribute__((ext_vector_type(8))) short bf16x8;
typedef __attribute__((ext_vector_type(4))) float f32x4;

// float -> bf16 bits, round-to-nearest-even (cold paths)
__device__ __forceinline__ unsigned short f2bf(float f) {
    union { float f; unsigned u; } uf{f};
    unsigned r = uf.u + 0x7fffu + ((uf.u >> 16) & 1u);
    return (unsigned short)(r >> 16);
}
// hot-path pack: v_cvt_pk_bf16_f32 via intrinsic (RNE, same results as f2bf)
__device__ __forceinline__ unsigned packcv(float a, float b) {
    __hip_bfloat162 h = __float22bfloat162_rn(make_float2(a, b));
    union { __hip_bfloat162 h; unsigned u; } c{h};
    return c.u;
}
__device__ __forceinline__ float bflo(unsigned u) {
    union { unsigned u; float f; } c{u << 16};
    return c.f;
}
__device__ __forceinline__ float bfhi(unsigned u) {
    union { unsigned u; float f; } c{u & 0xffff0000u};
    return c.f;
}

#define FMA8(A, vv, u) \
    A[0] = fmaf(vv, bflo(u.x), A[0]); A[1] = fmaf(vv, bfhi(u.x), A[1]); \
    A[2] = fmaf(vv, bflo(u.y), A[2]); A[3] = fmaf(vv, bfhi(u.y), A[3]); \
    A[4] = fmaf(vv, bflo(u.z), A[4]); A[5] = fmaf(vv, bfhi(u.z), A[5]); \
    A[6] = fmaf(vv, bflo(u.w), A[6]); A[7] = fmaf(vv, bfhi(u.w), A[7]);

// ---------------------------------------------------------------------------
// Kernel 0: rowptr[r] = (start,end) from sorted adj_rows; empty rows filled
//           from the gaps (no memset needed). Also converts W to bf16.
// ---------------------------------------------------------------------------
__global__ __launch_bounds__(256) void build_rowptr(const int* __restrict__ rows,
                                                    const float* __restrict__ W,
                                                    unsigned short* __restrict__ wbf,
                                                    int2* __restrict__ rowptr,
                                                    int e, int n) {
    int i = blockIdx.x * 256 + threadIdx.x;
    if (i < D * D) wbf[i] = f2bf(W[i]);
    if (i >= e) return;
    int r = rows[i];
    int prev = (i == 0) ? -1 : rows[i - 1];
    int next = (i == e - 1) ? n : rows[i + 1];
    if (prev != r) {
        rowptr[r].x = i;
        for (int q = prev + 1; q < r; ++q) rowptr[q] = make_int2(i, i);   // empty rows
    }
    if (next != r) {
        rowptr[r].y = i + 1;
        if (i == e - 1)
            for (int q = r + 1; q < n; ++q) rowptr[q] = make_int2(e, e); // trailing empties
    }
}

// ---------------------------------------------------------------------------
// Kernel 1: wi = bf16(x @ W^T), MFMA with swapped operands (D = W·x^T).
//   W staged once into swizzled LDS (32 KB); x fragments loaded per-lane
//   directly from global fp32 and packed via v_cvt_pk_bf16_f32.
// ---------------------------------------------------------------------------
__global__ __launch_bounds__(256) void gemm_mfma(const float* __restrict__ x,
                                                 const unsigned short* __restrict__ wbf,
                                                 unsigned short* __restrict__ wi,
                                                 int nrows) {
    __shared__ __align__(16) unsigned short Ws[128 * 128];   // 32 KB, swizzled

    const int tid = threadIdx.x;
    // stage W (already bf16): 16384 elems / 256 threads = 8 bf16 x 8 iters
#pragma unroll
    for (int it = 0; it < 8; ++it) {
        int elem = it * 2048 + tid * 8;
        int r = elem >> 7, k = elem & 127;
        int idx = (r * 128 + k) ^ ((r & 7) << 3);    // stays 8-elem aligned
        *(uint4*)&Ws[idx] = *(const uint4*)(wbf + elem);
    }
    __syncthreads();

    const int lane = tid & 63;
    const int row0 = blockIdx.x * 128 + (tid >> 6) * 32;  // wave's 32 nodes
    const int lrow = lane & 15;
    const int lk8 = (lane >> 4) * 8;

    // B operand: x fragments direct from global, cvt_pk packed
    bf16x8 xfrag[2][4];
#pragma unroll
    for (int xb = 0; xb < 2; ++xb)
#pragma unroll
        for (int kb = 0; kb < 4; ++kb) {
            int gr = min(row0 + xb * 16 + lrow, nrows - 1);
            const float4* p = (const float4*)(x + (size_t)gr * D + kb * 32 + lk8);
            float4 f0 = p[0], f1 = p[1];
            union { bf16x8 v; unsigned u[4]; } cv;
            cv.u[0] = packcv(f0.x, f0.y);
            cv.u[1] = packcv(f0.z, f0.w);
            cv.u[2] = packcv(f1.x, f1.y);
            cv.u[3] = packcv(f1.z, f1.w);
            xfrag[xb][kb] = cv.v;
        }

    f32x4 acc[2][8];
#pragma unroll
    for (int xb = 0; xb < 2; ++xb)
#pragma unroll
        for (int cb = 0; cb < 8; ++cb)
            acc[xb][cb] = (f32x4){0.f, 0.f, 0.f, 0.f};

#pragma unroll
    for (int cb = 0; cb < 8; ++cb) {
#pragma unroll
        for (int kb = 0; kb < 4; ++kb) {
            // A operand: W row (channel) from swizzled LDS
            int wrow = cb * 16 + lrow;
            int idx = (wrow * 128 + kb * 32 + lk8) ^ ((wrow & 7) << 3);
            bf16x8 wfrag = *(const bf16x8*)&Ws[idx];
            acc[0][cb] = __builtin_amdgcn_mfma_f32_16x16x32_bf16(wfrag, xfrag[0][kb], acc[0][cb], 0, 0, 0);
            acc[1][cb] = __builtin_amdgcn_mfma_f32_16x16x32_bf16(wfrag, xfrag[1][kb], acc[1][cb], 0, 0, 0);
        }
    }

    // D layout: col(lane&15)=node, row((lane>>4)*4+j)=channel
#pragma unroll
    for (int xb = 0; xb < 2; ++xb) {
        int g = row0 + xb * 16 + lrow;
        if (g < nrows) {
#pragma unroll
            for (int cb = 0; cb < 8; ++cb) {
                uint2 o;
                o.x = packcv(acc[xb][cb][0], acc[xb][cb][1]);
                o.y = packcv(acc[xb][cb][2], acc[xb][cb][3]);
                *(uint2*)(wi + (size_t)g * D + cb * 16 + (lane >> 4) * 4) = o;
            }
        }
    }
}

// ---------------------------------------------------------------------------
// Kernel 2: out[r] = relu(bias + sum vals[e]*wi[cols[e]])  (wi is bf16)
//   RPW rows/wave pipelined; per row, BOTH 16-edge quads issued up-front
//   -> 8 independent uint4 gathers in flight (covers rows <=32 edges).
// ---------------------------------------------------------------------------
__global__ __launch_bounds__(256) void spmm_relu(const unsigned short* __restrict__ wi,
                                                 const int2* __restrict__ rowptr,
                                                 const int* __restrict__ cols,
                                                 const float* __restrict__ vals,
                                                 const float* __restrict__ bias,
                                                 float* __restrict__ out,
                                                 int n) {
    const int lane = threadIdx.x & 63;
    const int R0 = (blockIdx.x * 4 + (threadIdx.x >> 6)) * RPW;
    if (R0 >= n) return;
    const int nr = min(RPW, n - R0);

    const int2 rp = rowptr[R0 + min(lane, nr - 1)];
    const int ch = (lane & 15) * 8;   // channel base this lane gathers
    const int sub = lane >> 4;        // lane's slot within each quad

    float4 b0 = *(const float4*)(bias + (lane & 15) * 8);
    float4 b1 = *(const float4*)(bias + (lane & 15) * 8 + 4);

    // prologue: stage row 0's first chunk (coalesced)
    int st = __shfl(rp.x, 0), en = __shfl(rp.y, 0);
    int c = 0; float v = 0.f;
    { int idx = st + lane; if (idx < en) { c = cols[idx]; v = vals[idx]; } }

    for (int j = 0; j < nr; ++j) {
        // prefetch next row's metadata (hides latency under this row)
        int st_n = 0, en_n = 0, c_n = 0; float v_n = 0.f;
        if (j + 1 < nr) {
            st_n = __shfl(rp.x, j + 1); en_n = __shfl(rp.y, j + 1);
            int idx = st_n + lane; if (idx < en_n) { c_n = cols[idx]; v_n = vals[idx]; }
        }

        float a0[8] = {0.f, 0.f, 0.f, 0.f, 0.f, 0.f, 0.f, 0.f};
        float a1[8] = {0.f, 0.f, 0.f, 0.f, 0.f, 0.f, 0.f, 0.f};

        const int cnt = min(en - st, 64);
        if (cnt > 0) {
            // edges [0,32): both quads issued together -> 8 gathers in flight.
            // Lanes whose edge index >= cnt read staged c=0/v=0 -> row-0 dummy.
            int cA[4], cB[4];
            float vA[4], vB[4];
#pragma unroll
            for (int p = 0; p < 4; ++p) {
                cA[p] = __shfl(c, sub + 4 * p);       vA[p] = __shfl(v, sub + 4 * p);
                cB[p] = __shfl(c, 16 + sub + 4 * p);  vB[p] = __shfl(v, 16 + sub + 4 * p);
            }
            uint4 uA[4], uB[4];
#pragma unroll
            for (int p = 0; p < 4; ++p) uA[p] = *(const uint4*)(wi + (size_t)cA[p] * D + ch);
#pragma unroll
            for (int p = 0; p < 4; ++p) uB[p] = *(const uint4*)(wi + (size_t)cB[p] * D + ch);
#pragma unroll
            for (int p = 0; p < 4; ++p) {
                FMA8(a0, vA[p], uA[p]);
                FMA8(a1, vB[p], uB[p]);
            }
            // edges [32, cnt): rare (rows with >32 edges)
            for (int E = 32; E < cnt; E += 16) {
#pragma unroll
                for (int p = 0; p < 4; ++p) {
                    int   cq = __shfl(c, E + sub + 4 * p);
                    float vq = __shfl(v, E + sub + 4 * p);
                    uint4 uq = *(const uint4*)(wi + (size_t)cq * D + ch);
                    FMA8(a0, vq, uq);
                }
            }
        }
        // very rare rows with >64 edges
        for (int base = st + 64; base < en; base += 64) {
            int cc = 0; float vv = 0.f;
            { int idx = base + lane; if (idx < en) { cc = cols[idx]; vv = vals[idx]; } }
            const int cnt2 = min(en - base, 64);
            for (int E = 0; E < cnt2; E += 16) {
#pragma unroll
                for (int p = 0; p < 4; ++p) {
                    int   cq = __shfl(cc, E + sub + 4 * p);
                    float vq = __shfl(vv, E + sub + 4 * p);
                    uint4 uq = *(const uint4*)(wi + (size_t)cq * D + ch);
                    FMA8(a1, vq, uq);
                }
            }
        }

        // reduce across the 4 sub-groups + store
        float r8[8];
#pragma unroll
        for (int t = 0; t < 8; ++t) {
            float s = a0[t] + a1[t];
            s += __shfl_xor(s, 16);
            s += __shfl_xor(s, 32);
            r8[t] = s;
        }
        if (lane < 16) {
            float4 o0, o1;
            o0.x = fmaxf(r8[0] + b0.x, 0.f);
            o0.y = fmaxf(r8[1] + b0.y, 0.f);
            o0.z = fmaxf(r8[2] + b0.z, 0.f);
            o0.w = fmaxf(r8[3] + b0.w, 0.f);
            o1.x = fmaxf(r8[4] + b1.x, 0.f);
            o1.y = fmaxf(r8[5] + b1.y, 0.f);
            o1.z = fmaxf(r8[6] + b1.z, 0.f);
            o1.w = fmaxf(r8[7] + b1.w, 0.f);
            *(float4*)(out + (size_t)(R0 + j) * D + lane * 8) = o0;
            *(float4*)(out + (size_t)(R0 + j) * D + lane * 8 + 4) = o1;
        }

        st = st_n; en = en_n; c = c_n; v = v_n;
    }
}

// ---------------------------------------------------------------------------
extern "C" void kernel_launch(void* const* d_in, const int* in_sizes, int n_in,
                              void* d_out, int out_size, void* d_ws, size_t ws_size,
                              hipStream_t stream) {
    const float* x        = (const float*)d_in[0];
    const int*   adj_rows = (const int*)d_in[1];
    const int*   adj_cols = (const int*)d_in[2];
    const float* adj_vals = (const float*)d_in[3];
    const float* weight   = (const float*)d_in[4];
    const float* bias     = (const float*)d_in[5];
    float*       out      = (float*)d_out;

    const int n = in_sizes[0] / D;   // 100000
    const int e = in_sizes[1];       // 1600000

    // workspace layout
    unsigned short* wi = (unsigned short*)d_ws;                 // n*128 bf16 = 25.6 MB
    size_t off = ((size_t)n * D * sizeof(unsigned short) + 255) & ~(size_t)255;
    int2* rowptr = (int2*)((char*)d_ws + off);                  // n int2 = 0.8 MB
    unsigned short* wbf = (unsigned short*)(rowptr + n);        // 32 KB bf16 W

    build_rowptr<<<(e + 255) / 256, 256, 0, stream>>>(adj_rows, weight, wbf,
                                                      rowptr, e, n);

    gemm_mfma<<<(n + 127) / 128, 256, 0, stream>>>(x, wbf, wi, n);

    spmm_relu<<<(n + 4 * RPW - 1) / (4 * RPW), 256, 0, stream>>>(
        wi, rowptr, adj_cols, adj_vals, bias, out, n);
}

// Round 8
// 94.309 us; speedup vs baseline: 1.7714x; 1.0194x over previous
//
#include <hip/hip_runtime.h>
#include <hip/hip_bf16.h>

#define D 128
#define RPW 2   // rows per wave in spmm

typedef __attribute__((ext_vector_type(8))) short bf16x8;
typedef __attribute__((ext_vector_type(4))) float f32x4;

// float -> bf16 bits, round-to-nearest-even (cold paths)
__device__ __forceinline__ unsigned short f2bf(float f) {
    union { float f; unsigned u; } uf{f};
    unsigned r = uf.u + 0x7fffu + ((uf.u >> 16) & 1u);
    return (unsigned short)(r >> 16);
}
// hot-path pack: v_cvt_pk_bf16_f32 via intrinsic (RNE)
__device__ __forceinline__ unsigned packcv(float a, float b) {
    __hip_bfloat162 h = __float22bfloat162_rn(make_float2(a, b));
    union { __hip_bfloat162 h; unsigned u; } c{h};
    return c.u;
}
__device__ __forceinline__ float bflo(unsigned u) {
    union { unsigned u; float f; } c{u << 16};
    return c.f;
}
__device__ __forceinline__ float bfhi(unsigned u) {
    union { unsigned u; float f; } c{u & 0xffff0000u};
    return c.f;
}
// decode packed (bf15<<17)|col
__device__ __forceinline__ int pc_col(unsigned u) { return (int)(u & 0x1FFFFu); }
__device__ __forceinline__ float pc_val(unsigned u) {
    union { unsigned u; float f; } c{(u >> 1) & 0xFFFF0000u};
    return c.f;
}

#define FMA8(A, vv, u) \
    A[0] = fmaf(vv, bflo(u.x), A[0]); A[1] = fmaf(vv, bfhi(u.x), A[1]); \
    A[2] = fmaf(vv, bflo(u.y), A[2]); A[3] = fmaf(vv, bfhi(u.y), A[3]); \
    A[4] = fmaf(vv, bflo(u.z), A[4]); A[5] = fmaf(vv, bfhi(u.z), A[5]); \
    A[6] = fmaf(vv, bflo(u.w), A[6]); A[7] = fmaf(vv, bfhi(u.w), A[7]);

// ---------------------------------------------------------------------------
// Kernel 0: rowptr from sorted adj_rows (+ gap fill); pack (val,col) -> u32;
//           convert W to bf16.
// ---------------------------------------------------------------------------
__global__ __launch_bounds__(256) void build_rowptr(const int* __restrict__ rows,
                                                    const int* __restrict__ cols,
                                                    const float* __restrict__ vals,
                                                    const float* __restrict__ W,
                                                    unsigned short* __restrict__ wbf,
                                                    unsigned* __restrict__ pc,
                                                    int2* __restrict__ rowptr,
                                                    int e, int n) {
    int i = blockIdx.x * 256 + threadIdx.x;
    if (i < D * D) wbf[i] = f2bf(W[i]);
    if (i >= e) return;

    // pack: vals in [0,1) -> positive bf16 (15 bits), col < 2^17
    pc[i] = ((unsigned)f2bf(vals[i]) << 17) | (unsigned)cols[i];

    int r = rows[i];
    int prev = (i == 0) ? -1 : rows[i - 1];
    int next = (i == e - 1) ? n : rows[i + 1];
    if (prev != r) {
        rowptr[r].x = i;
        for (int q = prev + 1; q < r; ++q) rowptr[q] = make_int2(i, i);   // empty rows
    }
    if (next != r) {
        rowptr[r].y = i + 1;
        if (i == e - 1)
            for (int q = r + 1; q < n; ++q) rowptr[q] = make_int2(e, e); // trailing empties
    }
}

// ---------------------------------------------------------------------------
// Kernel 1: wi = bf16(x @ W^T), MFMA with swapped operands (D = W·x^T).
//   x global loads issued FIRST (latency hides under W LDS-stage + barrier).
// ---------------------------------------------------------------------------
__global__ __launch_bounds__(256) void gemm_mfma(const float* __restrict__ x,
                                                 const unsigned short* __restrict__ wbf,
                                                 unsigned short* __restrict__ wi,
                                                 int nrows) {
    __shared__ __align__(16) unsigned short Ws[128 * 128];   // 32 KB, swizzled

    const int tid = threadIdx.x;
    const int lane = tid & 63;
    const int row0 = blockIdx.x * 128 + (tid >> 6) * 32;  // wave's 32 nodes
    const int lrow = lane & 15;
    const int lk8 = (lane >> 4) * 8;

    // 1) issue all x loads first
    float4 xf[2][4][2];
#pragma unroll
    for (int xb = 0; xb < 2; ++xb)
#pragma unroll
        for (int kb = 0; kb < 4; ++kb) {
            int gr = min(row0 + xb * 16 + lrow, nrows - 1);
            const float4* p = (const float4*)(x + (size_t)gr * D + kb * 32 + lk8);
            xf[xb][kb][0] = p[0];
            xf[xb][kb][1] = p[1];
        }

    // 2) stage W into swizzled LDS (overlaps with x loads in flight)
#pragma unroll
    for (int it = 0; it < 8; ++it) {
        int elem = it * 2048 + tid * 8;
        int r = elem >> 7, k = elem & 127;
        int idx = (r * 128 + k) ^ ((r & 7) << 3);
        *(uint4*)&Ws[idx] = *(const uint4*)(wbf + elem);
    }
    __syncthreads();

    // 3) convert x to bf16 fragments
    bf16x8 xfrag[2][4];
#pragma unroll
    for (int xb = 0; xb < 2; ++xb)
#pragma unroll
        for (int kb = 0; kb < 4; ++kb) {
            float4 f0 = xf[xb][kb][0], f1 = xf[xb][kb][1];
            union { bf16x8 v; unsigned u[4]; } cv;
            cv.u[0] = packcv(f0.x, f0.y);
            cv.u[1] = packcv(f0.z, f0.w);
            cv.u[2] = packcv(f1.x, f1.y);
            cv.u[3] = packcv(f1.z, f1.w);
            xfrag[xb][kb] = cv.v;
        }

    f32x4 acc[2][8];
#pragma unroll
    for (int xb = 0; xb < 2; ++xb)
#pragma unroll
        for (int cb = 0; cb < 8; ++cb)
            acc[xb][cb] = (f32x4){0.f, 0.f, 0.f, 0.f};

#pragma unroll
    for (int cb = 0; cb < 8; ++cb) {
#pragma unroll
        for (int kb = 0; kb < 4; ++kb) {
            int wrow = cb * 16 + lrow;
            int idx = (wrow * 128 + kb * 32 + lk8) ^ ((wrow & 7) << 3);
            bf16x8 wfrag = *(const bf16x8*)&Ws[idx];
            acc[0][cb] = __builtin_amdgcn_mfma_f32_16x16x32_bf16(wfrag, xfrag[0][kb], acc[0][cb], 0, 0, 0);
            acc[1][cb] = __builtin_amdgcn_mfma_f32_16x16x32_bf16(wfrag, xfrag[1][kb], acc[1][cb], 0, 0, 0);
        }
    }

    // D layout: col(lane&15)=node, row((lane>>4)*4+j)=channel
#pragma unroll
    for (int xb = 0; xb < 2; ++xb) {
        int g = row0 + xb * 16 + lrow;
        if (g < nrows) {
#pragma unroll
            for (int cb = 0; cb < 8; ++cb) {
                uint2 o;
                o.x = packcv(acc[xb][cb][0], acc[xb][cb][1]);
                o.y = packcv(acc[xb][cb][2], acc[xb][cb][3]);
                *(uint2*)(wi + (size_t)g * D + cb * 16 + (lane >> 4) * 4) = o;
            }
        }
    }
}

// ---------------------------------------------------------------------------
// Kernel 2: out[r] = relu(bias + sum vals[e]*wi[cols[e]])  (wi bf16, pc packed)
//   2 rows/wave (12.5k blocks -> full wave residency); per row both 16-edge
//   quads issued together -> 8 uint4 gathers in flight.
// ---------------------------------------------------------------------------
__global__ __launch_bounds__(256) void spmm_relu(const unsigned short* __restrict__ wi,
                                                 const int2* __restrict__ rowptr,
                                                 const unsigned* __restrict__ pc,
                                                 const float* __restrict__ bias,
                                                 float* __restrict__ out,
                                                 int n) {
    const int lane = threadIdx.x & 63;
    const int R0 = (blockIdx.x * 4 + (threadIdx.x >> 6)) * RPW;
    if (R0 >= n) return;
    const int nr = min(RPW, n - R0);

    const int2 rp = rowptr[R0 + min(lane, nr - 1)];
    const int ch = (lane & 15) * 8;   // channel base this lane gathers
    const int sub = lane >> 4;        // lane's slot within each quad

    float4 b0 = *(const float4*)(bias + (lane & 15) * 8);
    float4 b1 = *(const float4*)(bias + (lane & 15) * 8 + 4);

    // prologue: stage row 0's first chunk (coalesced)
    int st = __shfl(rp.x, 0), en = __shfl(rp.y, 0);
    unsigned u = 0;
    { int idx = st + lane; if (idx < en) u = pc[idx]; }

    for (int j = 0; j < nr; ++j) {
        // prefetch next row's metadata
        int st_n = 0, en_n = 0; unsigned u_n = 0;
        if (j + 1 < nr) {
            st_n = __shfl(rp.x, j + 1); en_n = __shfl(rp.y, j + 1);
            int idx = st_n + lane; if (idx < en_n) u_n = pc[idx];
        }

        float a0[8] = {0.f, 0.f, 0.f, 0.f, 0.f, 0.f, 0.f, 0.f};
        float a1[8] = {0.f, 0.f, 0.f, 0.f, 0.f, 0.f, 0.f, 0.f};

        const int cnt = min(en - st, 64);
        if (cnt > 0) {
            // edges [0,32): both quads issued together -> 8 gathers in flight.
            unsigned mA[4], mB[4];
#pragma unroll
            for (int p = 0; p < 4; ++p) {
                mA[p] = __shfl(u, sub + 4 * p);
                mB[p] = __shfl(u, 16 + sub + 4 * p);
            }
            uint4 uA[4], uB[4];
#pragma unroll
            for (int p = 0; p < 4; ++p) uA[p] = *(const uint4*)(wi + (size_t)pc_col(mA[p]) * D + ch);
#pragma unroll
            for (int p = 0; p < 4; ++p) uB[p] = *(const uint4*)(wi + (size_t)pc_col(mB[p]) * D + ch);
#pragma unroll
            for (int p = 0; p < 4; ++p) {
                FMA8(a0, pc_val(mA[p]), uA[p]);
                FMA8(a1, pc_val(mB[p]), uB[p]);
            }
            // edges [32, cnt): rows with >32 edges
            for (int E = 32; E < cnt; E += 16) {
#pragma unroll
                for (int p = 0; p < 4; ++p) {
                    unsigned m = __shfl(u, E + sub + 4 * p);
                    uint4 uq = *(const uint4*)(wi + (size_t)pc_col(m) * D + ch);
                    FMA8(a0, pc_val(m), uq);
                }
            }
        }
        // very rare rows with >64 edges
        for (int base = st + 64; base < en; base += 64) {
            unsigned uu = 0;
            { int idx = base + lane; if (idx < en) uu = pc[idx]; }
            const int cnt2 = min(en - base, 64);
            for (int E = 0; E < cnt2; E += 16) {
#pragma unroll
                for (int p = 0; p < 4; ++p) {
                    unsigned m = __shfl(uu, E + sub + 4 * p);
                    uint4 uq = *(const uint4*)(wi + (size_t)pc_col(m) * D + ch);
                    FMA8(a1, pc_val(m), uq);
                }
            }
        }

        // reduce across the 4 sub-groups + store
        float r8[8];
#pragma unroll
        for (int t = 0; t < 8; ++t) {
            float s = a0[t] + a1[t];
            s += __shfl_xor(s, 16);
            s += __shfl_xor(s, 32);
            r8[t] = s;
        }
        if (lane < 16) {
            float4 o0, o1;
            o0.x = fmaxf(r8[0] + b0.x, 0.f);
            o0.y = fmaxf(r8[1] + b0.y, 0.f);
            o0.z = fmaxf(r8[2] + b0.z, 0.f);
            o0.w = fmaxf(r8[3] + b0.w, 0.f);
            o1.x = fmaxf(r8[4] + b1.x, 0.f);
            o1.y = fmaxf(r8[5] + b1.y, 0.f);
            o1.z = fmaxf(r8[6] + b1.z, 0.f);
            o1.w = fmaxf(r8[7] + b1.w, 0.f);
            *(float4*)(out + (size_t)(R0 + j) * D + lane * 8) = o0;
            *(float4*)(out + (size_t)(R0 + j) * D + lane * 8 + 4) = o1;
        }

        st = st_n; en = en_n; u = u_n;
    }
}

// ---------------------------------------------------------------------------
extern "C" void kernel_launch(void* const* d_in, const int* in_sizes, int n_in,
                              void* d_out, int out_size, void* d_ws, size_t ws_size,
                              hipStream_t stream) {
    const float* x        = (const float*)d_in[0];
    const int*   adj_rows = (const int*)d_in[1];
    const int*   adj_cols = (const int*)d_in[2];
    const float* adj_vals = (const float*)d_in[3];
    const float* weight   = (const float*)d_in[4];
    const float* bias     = (const float*)d_in[5];
    float*       out      = (float*)d_out;

    const int n = in_sizes[0] / D;   // 100000
    const int e = in_sizes[1];       // 1600000

    // workspace layout
    unsigned short* wi = (unsigned short*)d_ws;                 // n*128 bf16 = 25.6 MB
    size_t off = ((size_t)n * D * sizeof(unsigned short) + 255) & ~(size_t)255;
    int2* rowptr = (int2*)((char*)d_ws + off);                  // n int2 = 0.8 MB
    unsigned* pc = (unsigned*)(rowptr + n);                     // e u32 = 6.4 MB
    unsigned short* wbf = (unsigned short*)(pc + e);            // 32 KB bf16 W

    build_rowptr<<<(e + 255) / 256, 256, 0, stream>>>(adj_rows, adj_cols, adj_vals,
                                                      weight, wbf, pc, rowptr, e, n);

    gemm_mfma<<<(n + 127) / 128, 256, 0, stream>>>(x, wbf, wi, n);

    spmm_relu<<<(n + 4 * RPW - 1) / (4 * RPW), 256, 0, stream>>>(
        wi, rowptr, pc, bias, out, n);
}